// Round 1
// baseline (1112.872 us; speedup 1.0000x reference)
//
#include <hip/hip_runtime.h>
#include <stdint.h>

#define N_ELEM (128*128*128)   // 2097152
#define NBINS 32

// ---------------- ws layout (bytes) ----------------
static constexpr size_t OFF_HIST2  = 0;                               // uint hist2[8][65536] = 2 MB
static constexpr size_t OFF_HIST1  = 8ull*65536ull*4ull;              // uint hist1[2][65536] = 512 KB
static constexpr size_t OFF_BUCKET = OFF_HIST1 + 2ull*65536ull*4ull;  // uint bucket[8]
static constexpr size_t OFF_RESID  = OFF_BUCKET + 8*4;                // uint resid[8]
static constexpr size_t OFF_SELVAL = OFF_RESID + 8*4;                 // float selval[8]
static constexpr size_t OFF_Q      = OFF_SELVAL + 8*4;                // float q[4] = {q01_t,q99_t,q01_p,q99_p}
static constexpr size_t OFF_ACC    = (OFF_Q + 4*4 + 7) & ~size_t(7); // double acc[2][66]
static constexpr size_t OFF_END    = OFF_ACC + 2*66*8;

// monotonic float <-> uint key
__device__ __forceinline__ uint32_t f2k(float x){
    uint32_t b = __float_as_uint(x);
    return (b & 0x80000000u) ? ~b : (b | 0x80000000u);
}
__device__ __forceinline__ float k2f(uint32_t k){
    uint32_t b = (k & 0x80000000u) ? (k & 0x7FFFFFFFu) : ~k;
    return __uint_as_float(b);
}

// ---- K1: histogram of top 16 key bits, both arrays ----
__global__ void k_hist1(const float* __restrict__ a0, const float* __restrict__ a1,
                        uint32_t* __restrict__ hist1){
    const float* src = blockIdx.y ? a1 : a0;
    uint32_t* h = hist1 + (size_t)blockIdx.y * 65536u;
    int stride = gridDim.x * blockDim.x;
    for (int i = blockIdx.x * blockDim.x + threadIdx.x; i < N_ELEM; i += stride){
        uint32_t k = f2k(src[i]);
        atomicAdd(&h[k >> 16], 1u);
    }
}

// ---- K2: scan hist1, find bucket+residual rank for 8 order statistics ----
__global__ void __launch_bounds__(1024) k_scan1(const uint32_t* __restrict__ hist1,
                                                uint32_t* __restrict__ bucket,
                                                uint32_t* __restrict__ resid){
    __shared__ uint32_t part[1024];
    const uint32_t R[4] = {20971u, 20972u, 2076179u, 2076180u};
    const int t = threadIdx.x;
    for (int a = 0; a < 2; ++a){
        const uint32_t* h = hist1 + (size_t)a * 65536u;
        uint32_t s = 0;
        for (int j = 0; j < 64; ++j) s += h[t*64 + j];
        part[t] = s;
        __syncthreads();
        for (int d = 1; d < 1024; d <<= 1){
            uint32_t add = (t >= d) ? part[t - d] : 0u;
            __syncthreads();
            part[t] += add;
            __syncthreads();
        }
        uint32_t c = part[t] - s;   // exclusive prefix of this thread's chunk
        for (int j = 0; j < 64; ++j){
            uint32_t cnt = h[t*64 + j];
            if (cnt){
                for (int ri = 0; ri < 4; ++ri){
                    uint32_t r = R[ri];
                    if (r >= c && r < c + cnt){
                        bucket[a*4 + ri] = (uint32_t)(t*64 + j);
                        resid [a*4 + ri] = r - c;
                    }
                }
            }
            c += cnt;
        }
        __syncthreads();
    }
}

// ---- K3: per-rank histogram of low 16 key bits (elements matching rank's bucket) ----
__global__ void k_hist2(const float* __restrict__ a0, const float* __restrict__ a1,
                        const uint32_t* __restrict__ bucket, uint32_t* __restrict__ hist2){
    const float* src = blockIdx.y ? a1 : a0;
    const int base = blockIdx.y * 4;
    uint32_t b0 = bucket[base+0], b1 = bucket[base+1], b2 = bucket[base+2], b3 = bucket[base+3];
    int stride = gridDim.x * blockDim.x;
    for (int i = blockIdx.x * blockDim.x + threadIdx.x; i < N_ELEM; i += stride){
        uint32_t k = f2k(src[i]);
        uint32_t hi = k >> 16, lo = k & 0xFFFFu;
        if (hi == b0) atomicAdd(&hist2[(size_t)(base+0)*65536u + lo], 1u);
        if (hi == b1) atomicAdd(&hist2[(size_t)(base+1)*65536u + lo], 1u);
        if (hi == b2) atomicAdd(&hist2[(size_t)(base+2)*65536u + lo], 1u);
        if (hi == b3) atomicAdd(&hist2[(size_t)(base+3)*65536u + lo], 1u);
    }
}

// ---- K4: scan hist2 per rank -> exact values -> interpolated quantiles ----
__global__ void __launch_bounds__(1024) k_scan2(const uint32_t* __restrict__ hist2,
                                                const uint32_t* __restrict__ bucket,
                                                const uint32_t* __restrict__ resid,
                                                float* __restrict__ selval,
                                                float* __restrict__ q){
    __shared__ uint32_t part[1024];
    const int t = threadIdx.x;
    for (int r = 0; r < 8; ++r){
        const uint32_t* h = hist2 + (size_t)r * 65536u;
        uint32_t s = 0;
        for (int j = 0; j < 64; ++j) s += h[t*64 + j];
        part[t] = s;
        __syncthreads();
        for (int d = 1; d < 1024; d <<= 1){
            uint32_t add = (t >= d) ? part[t - d] : 0u;
            __syncthreads();
            part[t] += add;
            __syncthreads();
        }
        uint32_t c = part[t] - s;
        uint32_t rr = resid[r];
        for (int j = 0; j < 64; ++j){
            uint32_t cnt = h[t*64 + j];
            if (cnt && rr >= c && rr < c + cnt){
                uint32_t key = (bucket[r] << 16) | (uint32_t)(t*64 + j);
                selval[r] = k2f(key);
            }
            c += cnt;
        }
        __syncthreads();
    }
    if (t == 0){
        // virtual index fracs: 0.01*(N-1)=20971.51 ; 0.99*(N-1)=2076179.49
        const double N1 = (double)(N_ELEM - 1);
        double f01 = 0.01 * N1 - 20971.0;
        double f99 = 0.99 * N1 - 2076179.0;
        double v0 = selval[0], v1 = selval[1], v2 = selval[2], v3 = selval[3];
        double v4 = selval[4], v5 = selval[5], v6 = selval[6], v7 = selval[7];
        q[0] = (float)(v0 + f01 * (v1 - v0));   // q01(y_true)
        q[1] = (float)(v2 + f99 * (v3 - v2));   // q99(y_true)
        q[2] = (float)(v4 + f01 * (v5 - v4));   // q01(y_pred)
        q[3] = (float)(v6 + f99 * (v7 - v6));   // q99(y_pred)
    }
}

// ---- K5: main Parzen-window accumulation (one direction per blockIdx.y) ----
__device__ __forceinline__ float wred(float v){
    #pragma unroll
    for (int o = 32; o > 0; o >>= 1) v += __shfl_down(v, o);
    return v;
}

__global__ void __launch_bounds__(256) k_main(const float* __restrict__ yt,
                                              const float* __restrict__ yp,
                                              const float* __restrict__ q,
                                              double* __restrict__ acc){
    const int dir = blockIdx.y;
    // dir0: pred=y_true, target=y_pred ; dir1: pred=y_pred, target=y_true
    const float* ysrc = dir ? yt : yp;   // target
    const float* xsrc = dir ? yp : yt;   // pred
    const float f_min = dir ? q[0] : q[2];
    const float f_max = dir ? q[1] : q[3];
    const float m_min = dir ? q[2] : q[0];
    const float m_max = dir ? q[3] : q[1];

    const float h     = (f_max - f_min) / 32.0f;
    const float vbc0  = f_min + 0.5f * h;
    const float vbcE  = f_max - 0.5f * h;
    const float step  = (vbcE - vbc0) / 31.0f;
    const float sigma = step * (1.0f / 2.355f);
    const float negpre = -1.0f / (2.0f * sigma * sigma);

    float vbc[NBINS];
    #pragma unroll
    for (int k = 0; k < NBINS; ++k) vbc[k] = vbc0 + step * (float)k;

    float s1[NBINS], s2[NBINS];
    #pragma unroll
    for (int k = 0; k < NBINS; ++k){ s1[k] = 0.f; s2[k] = 0.f; }
    float sx = 0.f, sxx = 0.f;

    const int stride = gridDim.x * blockDim.x;
    for (int i = blockIdx.x * blockDim.x + threadIdx.x; i < N_ELEM; i += stride){
        float yv = ysrc[i], xv = xsrc[i];
        float yc = fminf(fmaxf(yv, f_min), f_max);
        float xc = fminf(fmaxf(xv, m_min), m_max);
        sx += xc; sxx += xc * xc;
        #pragma unroll
        for (int k = 0; k < NBINS; ++k){
            float d = yc - vbc[k];
            float w = __expf(negpre * d * d);
            s1[k] += w;
            s2[k] += w * xc;
        }
    }

    // wave reduce then block reduce then one f64 atomic per accumulator
    const int lane = threadIdx.x & 63;
    const int wave = threadIdx.x >> 6;
    __shared__ float wp[4][66];
    #pragma unroll
    for (int k = 0; k < NBINS; ++k){ s1[k] = wred(s1[k]); s2[k] = wred(s2[k]); }
    sx = wred(sx); sxx = wred(sxx);
    if (lane == 0){
        #pragma unroll
        for (int k = 0; k < NBINS; ++k){ wp[wave][k] = s1[k]; wp[wave][32+k] = s2[k]; }
        wp[wave][64] = sx; wp[wave][65] = sxx;
    }
    __syncthreads();
    if (threadIdx.x < 66){
        float tsum = wp[0][threadIdx.x] + wp[1][threadIdx.x] + wp[2][threadIdx.x] + wp[3][threadIdx.x];
        atomicAdd(&acc[(size_t)dir*66 + threadIdx.x], (double)tsum);
    }
}

// ---- K6: scalar epilogue ----
__global__ void k_final(const double* __restrict__ acc, float* __restrict__ out){
    if (threadIdx.x == 0 && blockIdx.x == 0){
        const double eps = 1.1920928955078125e-07;  // finfo(float32).eps
        double res = 0.0;
        for (int dir = 0; dir < 2; ++dir){
            const double* A = acc + (size_t)dir*66;
            double sx = A[64], sxx = A[65];
            double tm = sx / (double)N_ELEM;
            double sumS1 = 0.0, bgv = 0.0;
            for (int k = 0; k < NBINS; ++k) sumS1 += A[k];
            for (int k = 0; k < NBINS; ++k){
                double mi = A[32+k] / (A[k] + eps);
                double d  = mi - tm;
                bgv += A[k] * d * d;
            }
            bgv /= (sumS1 + eps);
            double tv = (sxx - sx*sx/(double)N_ELEM) / (double)(N_ELEM - 1);
            res += bgv / (tv + eps);
        }
        out[0] = (float)(-0.5 * res);
    }
}

extern "C" void kernel_launch(void* const* d_in, const int* in_sizes, int n_in,
                              void* d_out, int out_size, void* d_ws, size_t ws_size,
                              hipStream_t stream){
    const float* yt = (const float*)d_in[0];
    const float* yp = (const float*)d_in[1];
    char* ws = (char*)d_ws;
    uint32_t* hist2  = (uint32_t*)(ws + OFF_HIST2);
    uint32_t* hist1  = (uint32_t*)(ws + OFF_HIST1);
    uint32_t* bucket = (uint32_t*)(ws + OFF_BUCKET);
    uint32_t* resid  = (uint32_t*)(ws + OFF_RESID);
    float*    selval = (float*)(ws + OFF_SELVAL);
    float*    q      = (float*)(ws + OFF_Q);
    double*   acc    = (double*)(ws + OFF_ACC);

    size_t zbytes = OFF_END < ws_size ? OFF_END : ws_size;
    hipMemsetAsync(d_ws, 0, zbytes, stream);

    dim3 gh(512, 2);
    k_hist1<<<gh, 256, 0, stream>>>(yt, yp, hist1);
    k_scan1<<<1, 1024, 0, stream>>>(hist1, bucket, resid);
    k_hist2<<<gh, 256, 0, stream>>>(yt, yp, bucket, hist2);
    k_scan2<<<1, 1024, 0, stream>>>(hist2, bucket, resid, selval, q);
    k_main<<<dim3(1024, 2), 256, 0, stream>>>(yt, yp, q, acc);
    k_final<<<1, 64, 0, stream>>>(acc, (float*)d_out);
}

// Round 2
// 166.081 us; speedup vs baseline: 6.7008x; 6.7008x over previous
//
#include <hip/hip_runtime.h>
#include <stdint.h>

#define N_ELEM (128*128*128)   // 2097152
#define NBINS 32

// ---------------- ws layout (bytes) ----------------
static constexpr size_t OFF_H12   = 0;                                 // uint hist12[2][4096]
static constexpr size_t OFF_H2    = OFF_H12 + 2ull*4096ull*4ull;       // uint hist2[8][1024]
static constexpr size_t OFF_H3    = OFF_H2  + 8ull*1024ull*4ull;       // uint hist3[8][1024]
static constexpr size_t OFF_B12   = OFF_H3  + 8ull*1024ull*4ull;       // uint bucket12[8]
static constexpr size_t OFF_R12   = OFF_B12 + 8*4;                     // uint resid12[8]
static constexpr size_t OFF_B22   = OFF_R12 + 8*4;                     // uint bucket22[8]
static constexpr size_t OFF_R22   = OFF_B22 + 8*4;                     // uint resid22[8]
static constexpr size_t OFF_Q     = OFF_R22 + 8*4;                     // float q[4]
static constexpr size_t OFF_ACC   = (OFF_Q + 4*4 + 7) & ~size_t(7);    // double acc[2][66]
static constexpr size_t OFF_END   = OFF_ACC + 2*66*8;

// monotonic float <-> uint key
__device__ __forceinline__ uint32_t f2k(float x){
    uint32_t b = __float_as_uint(x);
    return (b & 0x80000000u) ? ~b : (b | 0x80000000u);
}
__device__ __forceinline__ float k2f(uint32_t k){
    uint32_t b = (k & 0x80000000u) ? (k & 0x7FFFFFFFu) : ~k;
    return __uint_as_float(b);
}

// ---- P1: LDS-private 12-bit histogram (both arrays via blockIdx.y) ----
__global__ void __launch_bounds__(256) k_p1(const float* __restrict__ a0,
                                            const float* __restrict__ a1,
                                            uint32_t* __restrict__ hist12){
    __shared__ uint32_t lh[4096];
    for (int i = threadIdx.x; i < 4096; i += 256) lh[i] = 0;
    __syncthreads();
    const float4* s4 = (const float4*)(blockIdx.y ? a1 : a0);
    const int stride = gridDim.x * blockDim.x;
    for (int i = blockIdx.x * blockDim.x + threadIdx.x; i < N_ELEM/4; i += stride){
        float4 v = s4[i];
        atomicAdd(&lh[f2k(v.x) >> 20], 1u);
        atomicAdd(&lh[f2k(v.y) >> 20], 1u);
        atomicAdd(&lh[f2k(v.z) >> 20], 1u);
        atomicAdd(&lh[f2k(v.w) >> 20], 1u);
    }
    __syncthreads();
    uint32_t* gh = hist12 + (size_t)blockIdx.y * 4096u;
    for (int i = threadIdx.x; i < 4096; i += 256){
        uint32_t c = lh[i];
        if (c) atomicAdd(&gh[i], c);
    }
}

// ---- S1: scan 4096-bin hist per array, locate 8 order-statistic buckets ----
__global__ void __launch_bounds__(1024) k_s1(const uint32_t* __restrict__ hist12,
                                             uint32_t* __restrict__ bucket12,
                                             uint32_t* __restrict__ resid12){
    __shared__ uint32_t part[1024];
    const uint32_t R[4] = {20971u, 20972u, 2076179u, 2076180u};
    const int t = threadIdx.x;
    for (int a = 0; a < 2; ++a){
        const uint32_t* h = hist12 + (size_t)a * 4096u;
        uint32_t v[4];
        uint32_t s = 0;
        #pragma unroll
        for (int j = 0; j < 4; ++j){ v[j] = h[t*4 + j]; s += v[j]; }
        part[t] = s;
        __syncthreads();
        for (int d = 1; d < 1024; d <<= 1){
            uint32_t add = (t >= d) ? part[t - d] : 0u;
            __syncthreads();
            part[t] += add;
            __syncthreads();
        }
        uint32_t c = part[t] - s;
        #pragma unroll
        for (int j = 0; j < 4; ++j){
            uint32_t cnt = v[j];
            if (cnt){
                for (int ri = 0; ri < 4; ++ri){
                    uint32_t r = R[ri];
                    if (r >= c && r < c + cnt){
                        bucket12[a*4 + ri] = (uint32_t)(t*4 + j);
                        resid12 [a*4 + ri] = r - c;
                    }
                }
            }
            c += cnt;
        }
        __syncthreads();
    }
}

// ---- P2: refine bits [19:10] for the 4 ranks of each array ----
__global__ void __launch_bounds__(256) k_p2(const float* __restrict__ a0,
                                            const float* __restrict__ a1,
                                            const uint32_t* __restrict__ bucket12,
                                            uint32_t* __restrict__ hist2){
    __shared__ uint32_t lh[4][1024];
    for (int i = threadIdx.x; i < 4096; i += 256) ((uint32_t*)lh)[i] = 0;
    __syncthreads();
    const int base = blockIdx.y * 4;
    uint32_t b0 = bucket12[base+0], b1 = bucket12[base+1];
    uint32_t b2 = bucket12[base+2], b3 = bucket12[base+3];
    const float4* s4 = (const float4*)(blockIdx.y ? a1 : a0);
    const int stride = gridDim.x * blockDim.x;
    for (int i = blockIdx.x * blockDim.x + threadIdx.x; i < N_ELEM/4; i += stride){
        float4 v = s4[i];
        float vv[4] = {v.x, v.y, v.z, v.w};
        #pragma unroll
        for (int e = 0; e < 4; ++e){
            uint32_t k = f2k(vv[e]);
            uint32_t hi = k >> 20, lo = (k >> 10) & 1023u;
            if (hi == b0) atomicAdd(&lh[0][lo], 1u);
            if (hi == b1) atomicAdd(&lh[1][lo], 1u);
            if (hi == b2) atomicAdd(&lh[2][lo], 1u);
            if (hi == b3) atomicAdd(&lh[3][lo], 1u);
        }
    }
    __syncthreads();
    for (int i = threadIdx.x; i < 4096; i += 256){
        uint32_t c = ((uint32_t*)lh)[i];
        if (c) atomicAdd(&hist2[(size_t)base*1024u + i], c);
    }
}

// ---- S2: scan the 8 1024-bin refinements ----
__global__ void __launch_bounds__(1024) k_s2(const uint32_t* __restrict__ hist2,
                                             const uint32_t* __restrict__ bucket12,
                                             const uint32_t* __restrict__ resid12,
                                             uint32_t* __restrict__ bucket22,
                                             uint32_t* __restrict__ resid22){
    __shared__ uint32_t part[1024];
    const int t = threadIdx.x;
    for (int r = 0; r < 8; ++r){
        uint32_t s = hist2[(size_t)r*1024u + t];
        part[t] = s;
        __syncthreads();
        for (int d = 1; d < 1024; d <<= 1){
            uint32_t add = (t >= d) ? part[t - d] : 0u;
            __syncthreads();
            part[t] += add;
            __syncthreads();
        }
        uint32_t c = part[t] - s;
        uint32_t rr = resid12[r];
        if (s && rr >= c && rr < c + s){
            bucket22[r] = (bucket12[r] << 10) | (uint32_t)t;
            resid22[r]  = rr - c;
        }
        __syncthreads();
    }
}

// ---- P3: refine bits [9:0] ----
__global__ void __launch_bounds__(256) k_p3(const float* __restrict__ a0,
                                            const float* __restrict__ a1,
                                            const uint32_t* __restrict__ bucket22,
                                            uint32_t* __restrict__ hist3){
    __shared__ uint32_t lh[4][1024];
    for (int i = threadIdx.x; i < 4096; i += 256) ((uint32_t*)lh)[i] = 0;
    __syncthreads();
    const int base = blockIdx.y * 4;
    uint32_t b0 = bucket22[base+0], b1 = bucket22[base+1];
    uint32_t b2 = bucket22[base+2], b3 = bucket22[base+3];
    const float4* s4 = (const float4*)(blockIdx.y ? a1 : a0);
    const int stride = gridDim.x * blockDim.x;
    for (int i = blockIdx.x * blockDim.x + threadIdx.x; i < N_ELEM/4; i += stride){
        float4 v = s4[i];
        float vv[4] = {v.x, v.y, v.z, v.w};
        #pragma unroll
        for (int e = 0; e < 4; ++e){
            uint32_t k = f2k(vv[e]);
            uint32_t hi = k >> 10, lo = k & 1023u;
            if (hi == b0) atomicAdd(&lh[0][lo], 1u);
            if (hi == b1) atomicAdd(&lh[1][lo], 1u);
            if (hi == b2) atomicAdd(&lh[2][lo], 1u);
            if (hi == b3) atomicAdd(&lh[3][lo], 1u);
        }
    }
    __syncthreads();
    for (int i = threadIdx.x; i < 4096; i += 256){
        uint32_t c = ((uint32_t*)lh)[i];
        if (c) atomicAdd(&hist3[(size_t)base*1024u + i], c);
    }
}

// ---- S3: final scan -> exact values -> interpolated quantiles ----
__global__ void __launch_bounds__(1024) k_s3(const uint32_t* __restrict__ hist3,
                                             const uint32_t* __restrict__ bucket22,
                                             const uint32_t* __restrict__ resid22,
                                             float* __restrict__ q){
    __shared__ uint32_t part[1024];
    __shared__ float selval[8];
    const int t = threadIdx.x;
    for (int r = 0; r < 8; ++r){
        uint32_t s = hist3[(size_t)r*1024u + t];
        part[t] = s;
        __syncthreads();
        for (int d = 1; d < 1024; d <<= 1){
            uint32_t add = (t >= d) ? part[t - d] : 0u;
            __syncthreads();
            part[t] += add;
            __syncthreads();
        }
        uint32_t c = part[t] - s;
        uint32_t rr = resid22[r];
        if (s && rr >= c && rr < c + s){
            uint32_t key = (bucket22[r] << 10) | (uint32_t)t;
            selval[r] = k2f(key);
        }
        __syncthreads();
    }
    if (t == 0){
        const double N1 = (double)(N_ELEM - 1);
        double f01 = 0.01 * N1 - 20971.0;   // 0.51
        double f99 = 0.99 * N1 - 2076179.0; // 0.49
        double v0 = selval[0], v1 = selval[1], v2 = selval[2], v3 = selval[3];
        double v4 = selval[4], v5 = selval[5], v6 = selval[6], v7 = selval[7];
        q[0] = (float)(v0 + f01 * (v1 - v0));   // q01(y_true)
        q[1] = (float)(v2 + f99 * (v3 - v2));   // q99(y_true)
        q[2] = (float)(v4 + f01 * (v5 - v4));   // q01(y_pred)
        q[3] = (float)(v6 + f99 * (v7 - v6));   // q99(y_pred)
    }
}

// ---- K5: main Parzen-window accumulation (one direction per blockIdx.y) ----
__device__ __forceinline__ float wred(float v){
    #pragma unroll
    for (int o = 32; o > 0; o >>= 1) v += __shfl_down(v, o);
    return v;
}

__global__ void __launch_bounds__(256) k_main(const float* __restrict__ yt,
                                              const float* __restrict__ yp,
                                              const float* __restrict__ q,
                                              double* __restrict__ acc){
    const int dir = blockIdx.y;
    // dir0: pred=y_true, target=y_pred ; dir1: pred=y_pred, target=y_true
    const float4* ysrc = (const float4*)(dir ? yt : yp);   // target
    const float4* xsrc = (const float4*)(dir ? yp : yt);   // pred
    const float f_min = dir ? q[0] : q[2];
    const float f_max = dir ? q[1] : q[3];
    const float m_min = dir ? q[2] : q[0];
    const float m_max = dir ? q[3] : q[1];

    const float h     = (f_max - f_min) / 32.0f;
    const float vbc0  = f_min + 0.5f * h;
    const float vbcE  = f_max - 0.5f * h;
    const float step  = (vbcE - vbc0) / 31.0f;
    const float sigma = step * (1.0f / 2.355f);
    const float negpre = -1.0f / (2.0f * sigma * sigma);

    float vbc[NBINS];
    #pragma unroll
    for (int k = 0; k < NBINS; ++k) vbc[k] = vbc0 + step * (float)k;

    float s1[NBINS], s2[NBINS];
    #pragma unroll
    for (int k = 0; k < NBINS; ++k){ s1[k] = 0.f; s2[k] = 0.f; }
    float sx = 0.f, sxx = 0.f;

    const int stride = gridDim.x * blockDim.x;
    for (int i = blockIdx.x * blockDim.x + threadIdx.x; i < N_ELEM/4; i += stride){
        float4 yv4 = ysrc[i];
        float4 xv4 = xsrc[i];
        float yy[4] = {yv4.x, yv4.y, yv4.z, yv4.w};
        float xx[4] = {xv4.x, xv4.y, xv4.z, xv4.w};
        #pragma unroll
        for (int e = 0; e < 4; ++e){
            float yc = fminf(fmaxf(yy[e], f_min), f_max);
            float xc = fminf(fmaxf(xx[e], m_min), m_max);
            sx += xc; sxx += xc * xc;
            #pragma unroll
            for (int k = 0; k < NBINS; ++k){
                float d = yc - vbc[k];
                float w = __expf(negpre * d * d);
                s1[k] += w;
                s2[k] += w * xc;
            }
        }
    }

    const int lane = threadIdx.x & 63;
    const int wave = threadIdx.x >> 6;
    __shared__ float wp[4][66];
    #pragma unroll
    for (int k = 0; k < NBINS; ++k){ s1[k] = wred(s1[k]); s2[k] = wred(s2[k]); }
    sx = wred(sx); sxx = wred(sxx);
    if (lane == 0){
        #pragma unroll
        for (int k = 0; k < NBINS; ++k){ wp[wave][k] = s1[k]; wp[wave][32+k] = s2[k]; }
        wp[wave][64] = sx; wp[wave][65] = sxx;
    }
    __syncthreads();
    if (threadIdx.x < 66){
        float tsum = wp[0][threadIdx.x] + wp[1][threadIdx.x] + wp[2][threadIdx.x] + wp[3][threadIdx.x];
        atomicAdd(&acc[(size_t)dir*66 + threadIdx.x], (double)tsum);
    }
}

// ---- K6: scalar epilogue ----
__global__ void k_final(const double* __restrict__ acc, float* __restrict__ out){
    if (threadIdx.x == 0 && blockIdx.x == 0){
        const double eps = 1.1920928955078125e-07;  // finfo(float32).eps
        double res = 0.0;
        for (int dir = 0; dir < 2; ++dir){
            const double* A = acc + (size_t)dir*66;
            double sx = A[64], sxx = A[65];
            double tm = sx / (double)N_ELEM;
            double sumS1 = 0.0, bgv = 0.0;
            for (int k = 0; k < NBINS; ++k) sumS1 += A[k];
            for (int k = 0; k < NBINS; ++k){
                double mi = A[32+k] / (A[k] + eps);
                double d  = mi - tm;
                bgv += A[k] * d * d;
            }
            bgv /= (sumS1 + eps);
            double tv = (sxx - sx*sx/(double)N_ELEM) / (double)(N_ELEM - 1);
            res += bgv / (tv + eps);
        }
        out[0] = (float)(-0.5 * res);
    }
}

extern "C" void kernel_launch(void* const* d_in, const int* in_sizes, int n_in,
                              void* d_out, int out_size, void* d_ws, size_t ws_size,
                              hipStream_t stream){
    const float* yt = (const float*)d_in[0];
    const float* yp = (const float*)d_in[1];
    char* ws = (char*)d_ws;
    uint32_t* hist12   = (uint32_t*)(ws + OFF_H12);
    uint32_t* hist2    = (uint32_t*)(ws + OFF_H2);
    uint32_t* hist3    = (uint32_t*)(ws + OFF_H3);
    uint32_t* bucket12 = (uint32_t*)(ws + OFF_B12);
    uint32_t* resid12  = (uint32_t*)(ws + OFF_R12);
    uint32_t* bucket22 = (uint32_t*)(ws + OFF_B22);
    uint32_t* resid22  = (uint32_t*)(ws + OFF_R22);
    float*    q        = (float*)(ws + OFF_Q);
    double*   acc      = (double*)(ws + OFF_ACC);

    hipMemsetAsync(d_ws, 0, OFF_END, stream);

    dim3 gp(64, 2);
    k_p1<<<gp, 256, 0, stream>>>(yt, yp, hist12);
    k_s1<<<1, 1024, 0, stream>>>(hist12, bucket12, resid12);
    k_p2<<<gp, 256, 0, stream>>>(yt, yp, bucket12, hist2);
    k_s2<<<1, 1024, 0, stream>>>(hist2, bucket12, resid12, bucket22, resid22);
    k_p3<<<gp, 256, 0, stream>>>(yt, yp, bucket22, hist3);
    k_s3<<<1, 1024, 0, stream>>>(hist3, bucket22, resid22, q);
    k_main<<<dim3(1024, 2), 256, 0, stream>>>(yt, yp, q, acc);
    k_final<<<1, 64, 0, stream>>>(acc, (float*)d_out);
}